// Round 14
// baseline (589.220 us; speedup 1.0000x reference)
//
#include <hip/hip_runtime.h>
#include <hip/hip_bf16.h>
#include <math.h>

// WindowAttention: B=2048, C=256, H=8, d_k=32, wh=ww=7 -> L=49, nW=64.
// Reference reassigns v = k. Outputs: score (2048*256*49) then attn
// (2048*8*49*49), fp32, concatenated in d_out.
//
// MFMA design, R14: counted-vmcnt DOUBLE-BUFFERED pipeline (T3/T4 pattern).
// R13 was flat -> instruction-count lever exhausted; all pipes <40% busy,
// block lifetime ~20us vs ~3us critical path. Remaining serial term: every
// block paid a full vmcnt(0) stage drain with zero cross-pair overlap.
// Now: 2048 blocks x 4 bh-pairs each, two 25.6KB LDS buffers. At each
// iteration top, issue next pair's 7 global_load_lds into buf^1, then wait
// vmcnt(7) (NOT 0): this pair's stage (older, FIFO) is landed; next pair's
// flies under the whole compute phase. vmcnt(0) only on the last iteration.
// 6th lgkm barrier at loop end protects the buffer swap.
//
// Carried: 2 bh/iteration, 4 waves (R13); global_load_lds K+Q staging +
// K2-from-LDS (R11); LDS-routed contiguous writeout float2/float4 (R12/13);
// bf16 packed tables u16x8 (R13); exp2-fold + no-max softmax (R9/R10);
// lgkm-only barriers (R8); HW bf16 cvt (R8).
// Tripwires: WRITE >> 256MB = spill (R2-R4); absmax jump = pipeline race.

#define LW 49
#define NH 8

typedef short s16x8 __attribute__((ext_vector_type(8)));
typedef float f32x4 __attribute__((ext_vector_type(4)));
typedef unsigned short u16x8 __attribute__((ext_vector_type(8)));

union Frag { s16x8 v; unsigned short u[8]; };

__device__ __forceinline__ unsigned short f2bf(float x) {
    return __builtin_bit_cast(unsigned short, __float2bfloat16(x));
}
__device__ __forceinline__ float bf2f(unsigned short h) {
    return __uint_as_float(((unsigned)h) << 16);
}
// hi = bf16(x); lo = bf16(x - hi). 3-pass MFMA (Ah*Bh + Al*Bh + Ah*Bl)
// gives ~fp32 accuracy.
__device__ __forceinline__ void split8(const float* xf, Frag& hi, Frag& lo) {
    #pragma unroll
    for (int j = 0; j < 8; j++) {
        const unsigned short hb = f2bf(xf[j]);
        hi.u[j] = hb;
        lo.u[j] = f2bf(xf[j] - bf2f(hb));
    }
}

// LDS-only barrier: does NOT drain vmcnt (global loads/stores keep flying).
__device__ __forceinline__ void lds_barrier() {
    asm volatile("s_waitcnt lgkmcnt(0)" ::: "memory");
    __builtin_amdgcn_s_barrier();
    asm volatile("" ::: "memory");
    __builtin_amdgcn_sched_barrier(0);
}

__device__ __forceinline__ void load_lds16(const void* g, void* l) {
    __builtin_amdgcn_global_load_lds(
        (const __attribute__((address_space(1))) void*)g,
        (__attribute__((address_space(3))) void*)l, 16, 0, 0);
}

#define MFMA16(A, B, C) __builtin_amdgcn_mfma_f32_16x16x32_bf16((A), (B), (C), 0, 0, 0)

// ---------------- prep: bias & mask -> bf16, [x][mt][lane][nt*4+r] ----------
// Packed so one u16x8 (16B) load covers two nt-chunks. log2e-folded.
__global__ __launch_bounds__(256) void prep_frag_kernel(
    const float* __restrict__ mask, const float* __restrict__ table,
    const int* __restrict__ idx,
    unsigned short* __restrict__ biasB, unsigned short* __restrict__ maskB)
{
    const int i = blockIdx.x * 256 + threadIdx.x;
    const int NBF = 8 * 4096;        // 32768
    const int NMF = 64 * 4096;       // 262144
    const float L2E = 1.4426950408889634f;
    if (i < NBF) {
        const int h = i >> 12, rem = i & 4095;
        const int mt = rem >> 10, lane = (rem >> 4) & 63, e = rem & 15;
        const int nt = e >> 2, r = e & 3;
        const int t = mt * 16 + (lane >> 4) * 4 + r;
        const int s = nt * 16 + (lane & 15);
        const float v = (t < LW && s < LW)
                      ? table[idx[t * LW + s] * NH + h] * L2E : 0.f;
        biasB[i] = f2bf(v);
    } else if (i < NBF + NMF) {
        const int j = i - NBF;
        const int w2 = j >> 12, rem = j & 4095;
        const int mt = rem >> 10, lane = (rem >> 4) & 63, e = rem & 15;
        const int nt = e >> 2, r = e & 3;
        const int t = mt * 16 + (lane >> 4) * 4 + r;
        const int s = nt * 16 + (lane & 15);
        const float v = (t < LW && s < LW)
                      ? mask[w2 * (LW * LW) + t * LW + s] * L2E : 0.f;
        maskB[j] = f2bf(v);
    }
}

// ---------------- main: 4 waves, 2 bh per iteration, 4 iterations -----------
__global__ __launch_bounds__(256, 3) void wa_mfma_kernel(
    const float* __restrict__ q, const float* __restrict__ k,
    const unsigned short* __restrict__ biasB,
    const unsigned short* __restrict__ maskB,
    float* __restrict__ score_out, float* __restrict__ attn_out)
{
    // Two pair-buffers, each [sub][12800]:
    //  stage:    raw K fp32 [0,6400), raw Q fp32 [6400,12800)
    //  P planes: pHi u16 [0,6272)B, pLo u16 [6272,12544)B   (after phase 1)
    //  score:    f32 [0,6272)B                              (after phase 3)
    __shared__ __align__(16) char sRaw[2][2][12800];

    const int tid  = (int)threadIdx.x;    // 0..255
    const int wv   = __builtin_amdgcn_readfirstlane(tid >> 6);   // 0..3
    const int sub  = wv >> 1;             // which bh of the pair
    const int wvL  = wv & 1;              // role within the bh
    const int lane = tid & 63;
    const int l15  = lane & 15;
    const int g4   = lane >> 4;
    const int pairBase = blockIdx.x * 4;

    // Issue this wave's 7 global_load_lds for pair (pairBase+pi) into buf.
    auto do_stage = [&](int pi, int buf) {
        const int bhs = (pairBase + pi) * 2 + sub;
        const char* src = (wvL == 0)
            ? (const char*)(k + (size_t)bhs * (32 * LW))
            : (const char*)(q + (size_t)bhs * (32 * LW));
        char* dst = &sRaw[buf][sub][0] + wvL * 6400;
        #pragma unroll
        for (int i = 0; i < 6; i++)
            load_lds16(src + i * 1024 + lane * 16, dst + i * 1024);
        if (lane < 16) {
            // tail [6144,6400): lanes 8..15 write pad, gptr clamped in-bounds
            const int off = (lane < 8) ? lane * 16 : 112;
            load_lds16(src + 6144 + off, dst + 6144);
        }
    };

    do_stage(0, 0);                       // prologue: pair 0 -> buf 0

    #pragma unroll 1
    for (int p = 0; p < 4; p++) {
        const int cur = p & 1;
        // ==== pipeline top: issue next stage, counted wait on current ====
        if (p < 3) {
            do_stage(p + 1, cur ^ 1);
            // 7 newest VMEM = next stage; everything older (this pair's
            // stage, prev stores) is complete at <=7 outstanding.
            asm volatile("s_waitcnt vmcnt(7)" ::: "memory");
        } else {
            asm volatile("s_waitcnt vmcnt(0)" ::: "memory");
        }
        __builtin_amdgcn_s_barrier();
        asm volatile("" ::: "memory");
        __builtin_amdgcn_sched_barrier(0);

        const int bh = (pairBase + p) * 2 + sub;
        const int h  = bh & 7;
        const int w  = (bh >> 3) & 63;
        char* ldsBase = &sRaw[cur][sub][0];
        const float* sKf = (const float*)ldsBase;
        const float* sQf = (const float*)(ldsBase + 6400);

        // ==== bias/mask bf16 loads: u16x8 (16B) — fly across phase 1 ====
        u16x8 bq8[2][2], mq8[2][2];
        {
            const unsigned short* bF = biasB + (size_t)h * 4096;
            const unsigned short* mF = maskB + (size_t)w * 4096;
            #pragma unroll
            for (int mi = 0; mi < 2; mi++) {
                const int mt = wvL * 2 + mi;
                const u16x8* bp = (const u16x8*)(bF + mt * 1024 + lane * 16);
                const u16x8* mp = (const u16x8*)(mF + mt * 1024 + lane * 16);
                bq8[mi][0] = bp[0];
                bq8[mi][1] = bp[1];
                mq8[mi][0] = mp[0];
                mq8[mi][1] = mp[1];
            }
        }

        // ==== Q frags from LDS raw ====
        Frag Qh[2], Ql[2];
        #pragma unroll
        for (int mi = 0; mi < 2; mi++) {
            const int t  = (wvL * 2 + mi) * 16 + l15;
            const int tc = t < LW ? t : (LW - 1);
            float xf[8];
            #pragma unroll
            for (int j = 0; j < 8; j++) xf[j] = sQf[(g4 * 8 + j) * LW + tc];
            split8(xf, Qh[mi], Ql[mi]);
        }

        // ==== phase 1: S rows of this wave (K frags gathered per nt) ====
        f32x4 acc[2][4];
        #pragma unroll
        for (int mi = 0; mi < 2; mi++)
            #pragma unroll
            for (int nt = 0; nt < 4; nt++)
                #pragma unroll
                for (int r = 0; r < 4; r++) acc[mi][nt][r] = 0.f;

        #pragma unroll
        for (int nt = 0; nt < 4; nt++) {
            const int s  = nt * 16 + l15;
            const int sc = s < LW ? s : (LW - 1);
            float xf[8];
            #pragma unroll
            for (int j = 0; j < 8; j++) xf[j] = sKf[(g4 * 8 + j) * LW + sc];
            Frag Kh, Kl;
            split8(xf, Kh, Kl);
            #pragma unroll
            for (int mi = 0; mi < 2; mi++) {
                acc[mi][nt] = MFMA16(Qh[mi].v, Kh.v, acc[mi][nt]);
                acc[mi][nt] = MFMA16(Ql[mi].v, Kh.v, acc[mi][nt]);
                acc[mi][nt] = MFMA16(Qh[mi].v, Kl.v, acc[mi][nt]);
            }
        }

        // ==== K2 frags from the SAME raw K (before P pack overwrites) ====
        Frag K2h[2], K2l[2];
        {
            const int c = wvL * 16 + l15;              // c < 32 always
            #pragma unroll
            for (int ks = 0; ks < 2; ks++) {
                float xf[8];
                #pragma unroll
                for (int j = 0; j < 8; j++) {
                    const int s  = ks * 32 + g4 * 8 + j;
                    const int sc = s < LW ? s : (LW - 1);  // P at pad s is 0
                    xf[j] = sKf[c * LW + sc];
                }
                split8(xf, K2h[ks], K2l[ks]);
            }
        }

        // ==== scale2 + bias + mask (bf16 unpack); pad cols -> -1e30 ====
        const float scale2 = 0.17677669529663687f * 1.4426950408889634f;
        #pragma unroll
        for (int mi = 0; mi < 2; mi++) {
            #pragma unroll
            for (int nt = 0; nt < 4; nt++) {
                const bool pad = (nt * 16 + l15) >= LW;
                #pragma unroll
                for (int r = 0; r < 4; r++) {
                    const float bm = bf2f(bq8[mi][nt >> 1][(nt & 1) * 4 + r])
                                   + bf2f(mq8[mi][nt >> 1][(nt & 1) * 4 + r]);
                    const float v2 = fmaf(acc[mi][nt][r], scale2, bm);
                    acc[mi][nt][r] = pad ? -1e30f : v2;
                }
            }
        }

        // ==== softmax over s, no max-pass, native exp2 ====
        #pragma unroll
        for (int mi = 0; mi < 2; mi++) {
            #pragma unroll
            for (int r = 0; r < 4; r++) {
                float sm = 0.f;
                #pragma unroll
                for (int nt = 0; nt < 4; nt++) {
                    const float pp = __builtin_exp2f(acc[mi][nt][r]);
                    acc[mi][nt][r] = pp;
                    sm += pp;
                }
                sm += __shfl_xor(sm, 1);
                sm += __shfl_xor(sm, 2);
                sm += __shfl_xor(sm, 4);
                sm += __shfl_xor(sm, 8);
                const float inv = 1.0f / sm;
                #pragma unroll
                for (int nt = 0; nt < 4; nt++) acc[mi][nt][r] *= inv;
            }
        }

        lds_barrier();   // #2: raw-LDS reads done; reuse sub-buffers for P

        // ==== pack this wave's P rows into hi/lo planes (swizzled) ====
        unsigned short* sB = (unsigned short*)ldsBase;
        #pragma unroll
        for (int mi = 0; mi < 2; mi++) {
            #pragma unroll
            for (int r = 0; r < 4; r++) {
                const int t = (wvL * 2 + mi) * 16 + g4 * 4 + r;
                if (t < LW) {
                    #pragma unroll
                    for (int nt = 0; nt < 4; nt++) {
                        const int s = nt * 16 + l15;
                        const float pp = acc[mi][nt][r];
                        const unsigned short ph = f2bf(pp);
                        const unsigned short pl = f2bf(pp - bf2f(ph));
                        const unsigned idx = (unsigned)t * 64u
                            + ((((unsigned)s >> 3) ^ ((unsigned)t & 7u)) << 3)
                            + ((unsigned)s & 7u);
                        sB[idx]        = ph;
                        sB[3136 + idx] = pl;
                    }
                }
            }
        }

        lds_barrier();   // #3: P staged for BOTH bh

        // ==== attn writeout: combined pair stream, float2 (8B-aligned) ====
        {
            float2* dst2 = (float2*)(attn_out
                + (size_t)((pairBase + p) * 2) * (LW * LW));
            #pragma unroll
            for (int it = 0; it < 10; it++) {
                const int j = it * 256 + tid;
                if (j < LW * LW) {                     // 2401 slots
                    float v2[2];
                    #pragma unroll
                    for (int e = 0; e < 2; e++) {
                        const int g  = 2 * j + e;
                        const int sg = g >= LW * LW;   // which bh of pair
                        const int i2 = g - sg * (LW * LW);
                        const int t  = i2 / LW;        // magic-mul div
                        const int s  = i2 - t * LW;
                        const unsigned idx = (unsigned)t * 64u
                            + ((((unsigned)s >> 3) ^ ((unsigned)t & 7u)) << 3)
                            + ((unsigned)s & 7u);
                        const unsigned short* sBg =
                            (const unsigned short*)&sRaw[cur][sg][0];
                        v2[e] = bf2f(sBg[idx]) + bf2f(sBg[3136 + idx]);
                    }
                    dst2[j] = make_float2(v2[0], v2[1]);
                }
            }
        }

        // ==== phase 3: score(c,t) = sum_s K(c,s) P(t,s) ====
        f32x4 acc2[4];
        #pragma unroll
        for (int nt = 0; nt < 4; nt++)
            #pragma unroll
            for (int r = 0; r < 4; r++) acc2[nt][r] = 0.f;

        #pragma unroll
        for (int ntt = 0; ntt < 4; ntt++) {
            const int t  = ntt * 16 + l15;
            const int tr = t < LW ? t : (LW - 1);      // clamped dead cols
            #pragma unroll
            for (int ks = 0; ks < 2; ks++) {
                const unsigned base = (unsigned)tr * 64u
                    + (((unsigned)(ks * 4 + g4) ^ ((unsigned)tr & 7u)) << 3);
                Frag Ph, Pl;
                Ph.v = *(const s16x8*)&sB[base];        // ds_read_b128
                Pl.v = *(const s16x8*)&sB[3136 + base]; // ds_read_b128
                acc2[ntt] = MFMA16(K2h[ks].v, Ph.v, acc2[ntt]);
                acc2[ntt] = MFMA16(K2l[ks].v, Ph.v, acc2[ntt]);
                acc2[ntt] = MFMA16(K2h[ks].v, Pl.v, acc2[ntt]);
            }
        }

        lds_barrier();   // #4: all P reads (attn writeout + phase 3) done

        // ==== stage score f32 into [0,6272) of own sub (pHi dead) ====
        float* scf = (float*)ldsBase;
        #pragma unroll
        for (int ntt = 0; ntt < 4; ntt++) {
            const int t = ntt * 16 + l15;
            if (t < LW) {
                #pragma unroll
                for (int r = 0; r < 4; r++) {
                    const int c = wvL * 16 + g4 * 4 + r;
                    scf[c * LW + t] = acc2[ntt][r];
                }
            }
        }

        lds_barrier();   // #5: score staged for BOTH bh

        // ==== score writeout: combined pair stream, float4 ====
        {
            float4* dst4 = (float4*)(score_out
                + (size_t)((pairBase + p) * 2) * (32 * LW));
            #pragma unroll
            for (int it = 0; it < 4; it++) {
                const int j = it * 256 + tid;
                if (j < 784) {                         // 2*6272B/16B
                    const int sg = j >= 392;           // which bh of pair
                    const float4* src4 = (const float4*)&sRaw[cur][sg][0];
                    dst4[j] = src4[j - sg * 392];
                }
            }
        }

        lds_barrier();   // #6: score LDS reads retired before next stage
                         //     lands in buf cur^1 (buffer-swap guard)
    }
}

// ---------------- fallback (ws too small): VALU kernel ----------------------
__global__ __launch_bounds__(256, 4) void wa_fallback_kernel(
    const float* __restrict__ q, const float* __restrict__ k,
    const float* __restrict__ mask0, const float* __restrict__ table,
    const int* __restrict__ idx,
    float* __restrict__ score_out, float* __restrict__ attn_out)
{
    __shared__ float sPf[LW * LW];
    const int lane = threadIdx.x & 63;
    const int wv   = __builtin_amdgcn_readfirstlane((int)(threadIdx.x >> 6));
    const int bh   = blockIdx.x * 4 + wv;
    const int h    = bh & 7;
    const int w    = (bh >> 3) & 63;
    const int t    = lane;
    const int tc   = (t < LW) ? t : (LW - 1);

    const float* qp = q + (size_t)bh * (32 * LW);
    const float* kp = k + (size_t)bh * (32 * LW);

    float qreg[32];
    #pragma unroll
    for (int c = 0; c < 32; c++) qreg[c] = qp[c * LW + tc];

    float S[LW];
    #pragma unroll
    for (int s = 0; s < LW; s++) S[s] = 0.f;
    #pragma unroll
    for (int c = 0; c < 32; c++) {
        #pragma unroll
        for (int s = 0; s < LW; s++)
            S[s] = fmaf(qreg[c], kp[c * LW + s], S[s]);
    }

    const float scale = 0.17677669529663687f;
    const float* mrow = mask0 + (size_t)w * (LW * LW) + tc * LW;
    const int*   irow = idx + tc * LW;
    #pragma unroll
    for (int s = 0; s < LW; s++) {
        const float bm = table[irow[s] * NH + h] + mrow[s];
        S[s] = fmaf(S[s], scale, bm);
    }

    float m = S[0];
    #pragma unroll
    for (int s = 1; s < LW; s++) m = fmaxf(m, S[s]);
    float sum = 0.f;
    #pragma unroll
    for (int s = 0; s < LW; s++) { S[s] = __expf(S[s] - m); sum += S[s]; }
    const float invs = 1.0f / sum;
    #pragma unroll
    for (int s = 0; s < LW; s++) S[s] *= invs;

    float* attn_base = attn_out + (size_t)bh * (LW * LW);
    for (int turn = 0; turn < 4; turn++) {
        __syncthreads();
        if (turn == wv) {
            if (t < LW) {
                #pragma unroll
                for (int s = 0; s < LW; s++) sPf[t * LW + s] = S[s];
            }
            #pragma unroll
            for (int it = 0; it < 38; it++) {
                const int i = it * 64 + lane;
                if (i < LW * LW) attn_base[i] = sPf[i];
            }
        }
    }

    float* sc = score_out + (size_t)bh * (32 * LW);
    #pragma unroll
    for (int c = 0; c < 32; c++) {
        float a = 0.f;
        #pragma unroll
        for (int s = 0; s < LW; s++) a = fmaf(S[s], kp[c * LW + s], a);
        if (t < LW) sc[c * LW + t] = a;
    }
}

extern "C" void kernel_launch(void* const* d_in, const int* in_sizes, int n_in,
                              void* d_out, int out_size, void* d_ws, size_t ws_size,
                              hipStream_t stream) {
    const float* q     = (const float*)d_in[0];
    const float* k     = (const float*)d_in[1];
    // d_in[2] = v, unused: reference reassigns v = k
    const float* mask  = (const float*)d_in[3];
    const float* table = (const float*)d_in[4];
    const int*   idx   = (const int*)d_in[5];

    float* score_out = (float*)d_out;
    float* attn_out  = score_out + (size_t)2048 * 256 * 49;

    const size_t NBF = (size_t)8 * 4096;     // 32768 bf16 elems
    const size_t NMF = (size_t)64 * 4096;    // 262144 bf16 elems

    if (ws_size >= (NBF + NMF) * sizeof(unsigned short)) {
        unsigned short* biasB = (unsigned short*)d_ws;
        unsigned short* maskB = biasB + NBF;
        const int tot = (int)(NBF + NMF);
        prep_frag_kernel<<<(tot + 255) / 256, 256, 0, stream>>>(
            mask, table, idx, biasB, maskB);
        wa_mfma_kernel<<<2048, 256, 0, stream>>>(
            q, k, biasB, maskB, score_out, attn_out);
    } else {
        wa_fallback_kernel<<<4096, 256, 0, stream>>>(
            q, k, mask, table, idx, score_out, attn_out);
    }
}

// Round 15
// 453.354 us; speedup vs baseline: 1.2997x; 1.2997x over previous
//
#include <hip/hip_runtime.h>
#include <hip/hip_bf16.h>
#include <math.h>

// WindowAttention: B=2048, C=256, H=8, d_k=32, wh=ww=7 -> L=49, nW=64.
// Reference reassigns v = k. Outputs: score (2048*256*49) then attn
// (2048*8*49*49), fp32, concatenated in d_out.
//
// MFMA design, R15: STRAIGHT-LINE 2-deep pipeline. R14's loop version
// regressed from (a) loop-carried scratch spill (runtime-indexed buffers,
// R9 lesson repeated) and (b) WRONG vmcnt accounting: prev stores were
// OLDER than the counted ops, so vmcnt(7) drained them (no overlap).
// R15 instantiates the proven R13 body twice, double-buffered, no loop:
//   stageA(7) | tablesA(8) | stageB(7) | wait vmcnt(15)+bar |
//   tablesB(8) | computeA(+14 stores) | wait vmcnt(20)+bar | computeB
// FIFO-correct waits: vmcnt(15) retires exactly stageA; tablesA's use in
// computeA retires at vmcnt(15) leaving stageB flying; vmcnt(20) =
// tablesB(8) + MIN per-wave stores (12; execz-skipped tails make 12..14)
// retires stageB while A's stores stay in flight.
//
// Carried: 2 bh per pair-body, 4 waves (R13); global_load_lds K+Q staging
// + K2-from-LDS (R11); LDS-routed contiguous writeout float2/float4
// (R12/13); bf16 packed tables u16x8 (R13); exp2-fold + no-max softmax
// (R9/R10); lgkm-only barriers (R8); HW bf16 cvt (R8).
// Tripwires: FETCH/WRITE inflation = scratch (revert); absmax jump =
// vmcnt race (revert).

#define LW 49
#define NH 8

typedef short s16x8 __attribute__((ext_vector_type(8)));
typedef float f32x4 __attribute__((ext_vector_type(4)));
typedef unsigned short u16x8 __attribute__((ext_vector_type(8)));

union Frag { s16x8 v; unsigned short u[8]; };

__device__ __forceinline__ unsigned short f2bf(float x) {
    return __builtin_bit_cast(unsigned short, __float2bfloat16(x));
}
__device__ __forceinline__ float bf2f(unsigned short h) {
    return __uint_as_float(((unsigned)h) << 16);
}
// hi = bf16(x); lo = bf16(x - hi). 3-pass MFMA (Ah*Bh + Al*Bh + Ah*Bl)
// gives ~fp32 accuracy.
__device__ __forceinline__ void split8(const float* xf, Frag& hi, Frag& lo) {
    #pragma unroll
    for (int j = 0; j < 8; j++) {
        const unsigned short hb = f2bf(xf[j]);
        hi.u[j] = hb;
        lo.u[j] = f2bf(xf[j] - bf2f(hb));
    }
}

// LDS-only barrier: does NOT drain vmcnt (global loads/stores keep flying).
__device__ __forceinline__ void lds_barrier() {
    asm volatile("s_waitcnt lgkmcnt(0)" ::: "memory");
    __builtin_amdgcn_s_barrier();
    asm volatile("" ::: "memory");
    __builtin_amdgcn_sched_barrier(0);
}

__device__ __forceinline__ void load_lds16(const void* g, void* l) {
    __builtin_amdgcn_global_load_lds(
        (const __attribute__((address_space(1))) void*)g,
        (__attribute__((address_space(3))) void*)l, 16, 0, 0);
}

#define MFMA16(A, B, C) __builtin_amdgcn_mfma_f32_16x16x32_bf16((A), (B), (C), 0, 0, 0)

// ---------------- prep: bias & mask -> bf16, [x][mt][lane][nt*4+r] ----------
// Packed so one u16x8 (16B) load covers two nt-chunks. log2e-folded.
__global__ __launch_bounds__(256) void prep_frag_kernel(
    const float* __restrict__ mask, const float* __restrict__ table,
    const int* __restrict__ idx,
    unsigned short* __restrict__ biasB, unsigned short* __restrict__ maskB)
{
    const int i = blockIdx.x * 256 + threadIdx.x;
    const int NBF = 8 * 4096;        // 32768
    const int NMF = 64 * 4096;       // 262144
    const float L2E = 1.4426950408889634f;
    if (i < NBF) {
        const int h = i >> 12, rem = i & 4095;
        const int mt = rem >> 10, lane = (rem >> 4) & 63, e = rem & 15;
        const int nt = e >> 2, r = e & 3;
        const int t = mt * 16 + (lane >> 4) * 4 + r;
        const int s = nt * 16 + (lane & 15);
        const float v = (t < LW && s < LW)
                      ? table[idx[t * LW + s] * NH + h] * L2E : 0.f;
        biasB[i] = f2bf(v);
    } else if (i < NBF + NMF) {
        const int j = i - NBF;
        const int w2 = j >> 12, rem = j & 4095;
        const int mt = rem >> 10, lane = (rem >> 4) & 63, e = rem & 15;
        const int nt = e >> 2, r = e & 3;
        const int t = mt * 16 + (lane >> 4) * 4 + r;
        const int s = nt * 16 + (lane & 15);
        const float v = (t < LW && s < LW)
                      ? mask[w2 * (LW * LW) + t * LW + s] * L2E : 0.f;
        maskB[j] = f2bf(v);
    }
}

// ---- the R13-verified per-pair compute body (phase1..score writeout) -------
__device__ __forceinline__ void compute_pair(
    char* ldsPair,                    // [2][12800] region for this pair
    int pairIdx, int sub, int wvL, int lane, int l15, int g4, int tid,
    const u16x8 bq8[2][2], const u16x8 mq8[2][2],
    float* __restrict__ score_out, float* __restrict__ attn_out)
{
    char* ldsBase = ldsPair + sub * 12800;
    const float* sKf = (const float*)ldsBase;
    const float* sQf = (const float*)(ldsBase + 6400);

    // ==== Q frags from LDS raw ====
    Frag Qh[2], Ql[2];
    #pragma unroll
    for (int mi = 0; mi < 2; mi++) {
        const int t  = (wvL * 2 + mi) * 16 + l15;
        const int tc = t < LW ? t : (LW - 1);
        float xf[8];
        #pragma unroll
        for (int j = 0; j < 8; j++) xf[j] = sQf[(g4 * 8 + j) * LW + tc];
        split8(xf, Qh[mi], Ql[mi]);
    }

    // ==== phase 1: S rows of this wave (K frags gathered per nt) ====
    f32x4 acc[2][4];
    #pragma unroll
    for (int mi = 0; mi < 2; mi++)
        #pragma unroll
        for (int nt = 0; nt < 4; nt++)
            #pragma unroll
            for (int r = 0; r < 4; r++) acc[mi][nt][r] = 0.f;

    #pragma unroll
    for (int nt = 0; nt < 4; nt++) {
        const int s  = nt * 16 + l15;
        const int sc = s < LW ? s : (LW - 1);
        float xf[8];
        #pragma unroll
        for (int j = 0; j < 8; j++) xf[j] = sKf[(g4 * 8 + j) * LW + sc];
        Frag Kh, Kl;
        split8(xf, Kh, Kl);
        #pragma unroll
        for (int mi = 0; mi < 2; mi++) {
            acc[mi][nt] = MFMA16(Qh[mi].v, Kh.v, acc[mi][nt]);
            acc[mi][nt] = MFMA16(Ql[mi].v, Kh.v, acc[mi][nt]);
            acc[mi][nt] = MFMA16(Qh[mi].v, Kl.v, acc[mi][nt]);
        }
    }

    // ==== K2 frags from the SAME raw K (before P pack overwrites) ====
    Frag K2h[2], K2l[2];
    {
        const int c = wvL * 16 + l15;                  // c < 32 always
        #pragma unroll
        for (int ks = 0; ks < 2; ks++) {
            float xf[8];
            #pragma unroll
            for (int j = 0; j < 8; j++) {
                const int s  = ks * 32 + g4 * 8 + j;
                const int sc = s < LW ? s : (LW - 1);  // P at pad s is 0
                xf[j] = sKf[c * LW + sc];
            }
            split8(xf, K2h[ks], K2l[ks]);
        }
    }

    // ==== scale2 + bias + mask (bf16 unpack); pad cols -> -1e30 ====
    const float scale2 = 0.17677669529663687f * 1.4426950408889634f;
    #pragma unroll
    for (int mi = 0; mi < 2; mi++) {
        #pragma unroll
        for (int nt = 0; nt < 4; nt++) {
            const bool pad = (nt * 16 + l15) >= LW;
            #pragma unroll
            for (int r = 0; r < 4; r++) {
                const float bm = bf2f(bq8[mi][nt >> 1][(nt & 1) * 4 + r])
                               + bf2f(mq8[mi][nt >> 1][(nt & 1) * 4 + r]);
                const float v2 = fmaf(acc[mi][nt][r], scale2, bm);
                acc[mi][nt][r] = pad ? -1e30f : v2;
            }
        }
    }

    // ==== softmax over s, no max-pass, native exp2 ====
    #pragma unroll
    for (int mi = 0; mi < 2; mi++) {
        #pragma unroll
        for (int r = 0; r < 4; r++) {
            float sm = 0.f;
            #pragma unroll
            for (int nt = 0; nt < 4; nt++) {
                const float pp = __builtin_exp2f(acc[mi][nt][r]);
                acc[mi][nt][r] = pp;
                sm += pp;
            }
            sm += __shfl_xor(sm, 1);
            sm += __shfl_xor(sm, 2);
            sm += __shfl_xor(sm, 4);
            sm += __shfl_xor(sm, 8);
            const float inv = 1.0f / sm;
            #pragma unroll
            for (int nt = 0; nt < 4; nt++) acc[mi][nt][r] *= inv;
        }
    }

    lds_barrier();   // raw-LDS reads done (all waves); reuse buffers for P

    // ==== pack this wave's P rows into hi/lo planes (swizzled) ====
    unsigned short* sB = (unsigned short*)ldsBase;
    #pragma unroll
    for (int mi = 0; mi < 2; mi++) {
        #pragma unroll
        for (int r = 0; r < 4; r++) {
            const int t = (wvL * 2 + mi) * 16 + g4 * 4 + r;
            if (t < LW) {
                #pragma unroll
                for (int nt = 0; nt < 4; nt++) {
                    const int s = nt * 16 + l15;
                    const float pp = acc[mi][nt][r];
                    const unsigned short ph = f2bf(pp);
                    const unsigned short pl = f2bf(pp - bf2f(ph));
                    const unsigned idx = (unsigned)t * 64u
                        + ((((unsigned)s >> 3) ^ ((unsigned)t & 7u)) << 3)
                        + ((unsigned)s & 7u);
                    sB[idx]        = ph;
                    sB[3136 + idx] = pl;
                }
            }
        }
    }

    lds_barrier();   // P staged for BOTH bh

    // ==== attn writeout: combined pair stream, float2 (8B-aligned) ====
    {
        float2* dst2 = (float2*)(attn_out + (size_t)(pairIdx * 2) * (LW * LW));
        #pragma unroll
        for (int it = 0; it < 10; it++) {
            const int j = it * 256 + tid;
            if (j < LW * LW) {                         // 2401 slots
                float v2[2];
                #pragma unroll
                for (int e = 0; e < 2; e++) {
                    const int g  = 2 * j + e;
                    const int sg = g >= LW * LW;       // which bh of pair
                    const int i2 = g - sg * (LW * LW);
                    const int t  = i2 / LW;            // magic-mul div
                    const int s  = i2 - t * LW;
                    const unsigned idx = (unsigned)t * 64u
                        + ((((unsigned)s >> 3) ^ ((unsigned)t & 7u)) << 3)
                        + ((unsigned)s & 7u);
                    const unsigned short* sBg =
                        (const unsigned short*)(ldsPair + sg * 12800);
                    v2[e] = bf2f(sBg[idx]) + bf2f(sBg[3136 + idx]);
                }
                dst2[j] = make_float2(v2[0], v2[1]);
            }
        }
    }

    // ==== phase 3: score(c,t) = sum_s K(c,s) P(t,s) ====
    f32x4 acc2[4];
    #pragma unroll
    for (int nt = 0; nt < 4; nt++)
        #pragma unroll
        for (int r = 0; r < 4; r++) acc2[nt][r] = 0.f;

    #pragma unroll
    for (int ntt = 0; ntt < 4; ntt++) {
        const int t  = ntt * 16 + l15;
        const int tr = t < LW ? t : (LW - 1);          // clamped dead cols
        #pragma unroll
        for (int ks = 0; ks < 2; ks++) {
            const unsigned base = (unsigned)tr * 64u
                + (((unsigned)(ks * 4 + g4) ^ ((unsigned)tr & 7u)) << 3);
            Frag Ph, Pl;
            Ph.v = *(const s16x8*)&sB[base];            // ds_read_b128
            Pl.v = *(const s16x8*)&sB[3136 + base];     // ds_read_b128
            acc2[ntt] = MFMA16(K2h[ks].v, Ph.v, acc2[ntt]);
            acc2[ntt] = MFMA16(K2l[ks].v, Ph.v, acc2[ntt]);
            acc2[ntt] = MFMA16(K2h[ks].v, Pl.v, acc2[ntt]);
        }
    }

    lds_barrier();   // all P reads (attn writeout + phase 3) done

    // ==== stage score f32 into [0,6272) of own sub (pHi dead) ====
    float* scf = (float*)ldsBase;
    #pragma unroll
    for (int ntt = 0; ntt < 4; ntt++) {
        const int t = ntt * 16 + l15;
        if (t < LW) {
            #pragma unroll
            for (int r = 0; r < 4; r++) {
                const int c = wvL * 16 + g4 * 4 + r;
                scf[c * LW + t] = acc2[ntt][r];
            }
        }
    }

    lds_barrier();   // score staged for BOTH bh

    // ==== score writeout: combined pair stream, float4 ====
    {
        float4* dst4 = (float4*)(score_out + (size_t)(pairIdx * 2) * (32 * LW));
        #pragma unroll
        for (int it = 0; it < 4; it++) {
            const int j = it * 256 + tid;
            if (j < 784) {                             // 2*6272B/16B
                const int sg = j >= 392;               // which bh of pair
                const float4* src4 = (const float4*)(ldsPair + sg * 12800);
                dst4[j] = src4[j - sg * 392];
            }
        }
    }
}

// ---------------- main: 4 waves, straight-line 2-pair pipeline --------------
__global__ __launch_bounds__(256, 3) void wa_mfma_kernel(
    const float* __restrict__ q, const float* __restrict__ k,
    const unsigned short* __restrict__ biasB,
    const unsigned short* __restrict__ maskB,
    float* __restrict__ score_out, float* __restrict__ attn_out)
{
    __shared__ __align__(16) char sRawA[2][12800];
    __shared__ __align__(16) char sRawB[2][12800];

    const int tid  = (int)threadIdx.x;    // 0..255
    const int wv   = __builtin_amdgcn_readfirstlane(tid >> 6);   // 0..3
    const int sub  = wv >> 1;
    const int wvL  = wv & 1;
    const int lane = tid & 63;
    const int l15  = lane & 15;
    const int g4   = lane >> 4;
    const int pairA = blockIdx.x * 2;
    const int pairB = pairA + 1;

    // ---- stage A: 7 global_load_lds per wave ----
    {
        const int bhs = pairA * 2 + sub;
        const char* src = (wvL == 0)
            ? (const char*)(k + (size_t)bhs * (32 * LW))
            : (const char*)(q + (size_t)bhs * (32 * LW));
        char* dst = &sRawA[sub][0] + wvL * 6400;
        #pragma unroll
        for (int i = 0; i < 6; i++)
            load_lds16(src + i * 1024 + lane * 16, dst + i * 1024);
        if (lane < 16) {
            const int off = (lane < 8) ? lane * 16 : 112;
            load_lds16(src + 6144 + off, dst + 6144);
        }
    }
    __builtin_amdgcn_sched_barrier(0);

    // ---- tables A: 8 u16x8 loads (issued BEFORE stageB so consuming
    //      them later never forces stageB to retire — vmcnt is FIFO) ----
    u16x8 bq8A[2][2], mq8A[2][2];
    {
        const int bh = pairA * 2 + sub;
        const unsigned short* bF = biasB + (size_t)(bh & 7) * 4096;
        const unsigned short* mF = maskB + (size_t)((bh >> 3) & 63) * 4096;
        #pragma unroll
        for (int mi = 0; mi < 2; mi++) {
            const int mt = wvL * 2 + mi;
            const u16x8* bp = (const u16x8*)(bF + mt * 1024 + lane * 16);
            const u16x8* mp = (const u16x8*)(mF + mt * 1024 + lane * 16);
            bq8A[mi][0] = bp[0];
            bq8A[mi][1] = bp[1];
            mq8A[mi][0] = mp[0];
            mq8A[mi][1] = mp[1];
        }
    }
    __builtin_amdgcn_sched_barrier(0);

    // ---- stage B: 7 global_load_lds per wave (flies under computeA) ----
    {
        const int bhs = pairB * 2 + sub;
        const char* src = (wvL == 0)
            ? (const char*)(k + (size_t)bhs * (32 * LW))
            : (const char*)(q + (size_t)bhs * (32 * LW));
        char* dst = &sRawB[sub][0] + wvL * 6400;
        #pragma unroll
        for (int i = 0; i < 6; i++)
            load_lds16(src + i * 1024 + lane * 16, dst + i * 1024);
        if (lane < 16) {
            const int off = (lane < 8) ? lane * 16 : 112;
            load_lds16(src + 6144 + off, dst + 6144);
        }
    }
    __builtin_amdgcn_sched_barrier(0);

    // ---- barrier A: retire exactly stageA (15 newer: tablesA+stageB) ----
    asm volatile("s_waitcnt vmcnt(15)" ::: "memory");
    __builtin_amdgcn_s_barrier();
    asm volatile("" ::: "memory");
    __builtin_amdgcn_sched_barrier(0);

    // ---- tables B: issued now (after stageB, before A's stores) ----
    u16x8 bq8B[2][2], mq8B[2][2];
    {
        const int bh = pairB * 2 + sub;
        const unsigned short* bF = biasB + (size_t)(bh & 7) * 4096;
        const unsigned short* mF = maskB + (size_t)((bh >> 3) & 63) * 4096;
        #pragma unroll
        for (int mi = 0; mi < 2; mi++) {
            const int mt = wvL * 2 + mi;
            const u16x8* bp = (const u16x8*)(bF + mt * 1024 + lane * 16);
            const u16x8* mp = (const u16x8*)(mF + mt * 1024 + lane * 16);
            bq8B[mi][0] = bp[0];
            bq8B[mi][1] = bp[1];
            mq8B[mi][0] = mp[0];
            mq8B[mi][1] = mp[1];
        }
    }
    __builtin_amdgcn_sched_barrier(0);

    // ---- compute pair A (issues its 14 stores; stageB still flying) ----
    compute_pair(&sRawA[0][0], pairA, sub, wvL, lane, l15, g4, tid,
                 bq8A, mq8A, score_out, attn_out);

    // ---- barrier B: retire stageB, keep A's stores in flight ----
    // newer-than-stageB minimum per wave = tablesB(8) + stores(>=12:
    // execz-skipped tail stores make per-wave counts 12..14).
    asm volatile("s_waitcnt vmcnt(20)" ::: "memory");
    __builtin_amdgcn_s_barrier();
    asm volatile("" ::: "memory");
    __builtin_amdgcn_sched_barrier(0);

    // ---- compute pair B ----
    compute_pair(&sRawB[0][0], pairB, sub, wvL, lane, l15, g4, tid,
                 bq8B, mq8B, score_out, attn_out);
}

// ---------------- fallback (ws too small): VALU kernel ----------------------
__global__ __launch_bounds__(256, 4) void wa_fallback_kernel(
    const float* __restrict__ q, const float* __restrict__ k,
    const float* __restrict__ mask0, const float* __restrict__ table,
    const int* __restrict__ idx,
    float* __restrict__ score_out, float* __restrict__ attn_out)
{
    __shared__ float sPf[LW * LW];
    const int lane = threadIdx.x & 63;
    const int wv   = __builtin_amdgcn_readfirstlane((int)(threadIdx.x >> 6));
    const int bh   = blockIdx.x * 4 + wv;
    const int h    = bh & 7;
    const int w    = (bh >> 3) & 63;
    const int t    = lane;
    const int tc   = (t < LW) ? t : (LW - 1);

    const float* qp = q + (size_t)bh * (32 * LW);
    const float* kp = k + (size_t)bh * (32 * LW);

    float qreg[32];
    #pragma unroll
    for (int c = 0; c < 32; c++) qreg[c] = qp[c * LW + tc];

    float S[LW];
    #pragma unroll
    for (int s = 0; s < LW; s++) S[s] = 0.f;
    #pragma unroll
    for (int c = 0; c < 32; c++) {
        #pragma unroll
        for (int s = 0; s < LW; s++)
            S[s] = fmaf(qreg[c], kp[c * LW + s], S[s]);
    }

    const float scale = 0.17677669529663687f;
    const float* mrow = mask0 + (size_t)w * (LW * LW) + tc * LW;
    const int*   irow = idx + tc * LW;
    #pragma unroll
    for (int s = 0; s < LW; s++) {
        const float bm = table[irow[s] * NH + h] + mrow[s];
        S[s] = fmaf(S[s], scale, bm);
    }

    float m = S[0];
    #pragma unroll
    for (int s = 1; s < LW; s++) m = fmaxf(m, S[s]);
    float sum = 0.f;
    #pragma unroll
    for (int s = 0; s < LW; s++) { S[s] = __expf(S[s] - m); sum += S[s]; }
    const float invs = 1.0f / sum;
    #pragma unroll
    for (int s = 0; s < LW; s++) S[s] *= invs;

    float* attn_base = attn_out + (size_t)bh * (LW * LW);
    for (int turn = 0; turn < 4; turn++) {
        __syncthreads();
        if (turn == wv) {
            if (t < LW) {
                #pragma unroll
                for (int s = 0; s < LW; s++) sPf[t * LW + s] = S[s];
            }
            #pragma unroll
            for (int it = 0; it < 38; it++) {
                const int i = it * 64 + lane;
                if (i < LW * LW) attn_base[i] = sPf[i];
            }
        }
    }

    float* sc = score_out + (size_t)bh * (32 * LW);
    #pragma unroll
    for (int c = 0; c < 32; c++) {
        float a = 0.f;
        #pragma unroll
        for (int s = 0; s < LW; s++) a = fmaf(S[s], kp[c * LW + s], a);
        if (t < LW) sc[c * LW + t] = a;
    }
}

extern "C" void kernel_launch(void* const* d_in, const int* in_sizes, int n_in,
                              void* d_out, int out_size, void* d_ws, size_t ws_size,
                              hipStream_t stream) {
    const float* q     = (const float*)d_in[0];
    const float* k     = (const float*)d_in[1];
    // d_in[2] = v, unused: reference reassigns v = k
    const float* mask  = (const float*)d_in[3];
    const float* table = (const float*)d_in[4];
    const int*   idx   = (const int*)d_in[5];

    float* score_out = (float*)d_out;
    float* attn_out  = score_out + (size_t)2048 * 256 * 49;

    const size_t NBF = (size_t)8 * 4096;     // 32768 bf16 elems
    const size_t NMF = (size_t)64 * 4096;    // 262144 bf16 elems

    if (ws_size >= (NBF + NMF) * sizeof(unsigned short)) {
        unsigned short* biasB = (unsigned short*)d_ws;
        unsigned short* maskB = biasB + NBF;
        const int tot = (int)(NBF + NMF);
        prep_frag_kernel<<<(tot + 255) / 256, 256, 0, stream>>>(
            mask, table, idx, biasB, maskB);
        wa_mfma_kernel<<<4096, 256, 0, stream>>>(
            q, k, biasB, maskB, score_out, attn_out);
    } else {
        wa_fallback_kernel<<<4096, 256, 0, stream>>>(
            q, k, mask, table, idx, score_out, attn_out);
    }
}

// Round 16
// 444.179 us; speedup vs baseline: 1.3265x; 1.0207x over previous
//
#include <hip/hip_runtime.h>
#include <hip/hip_bf16.h>
#include <math.h>

// WindowAttention: B=2048, C=256, H=8, d_k=32, wh=ww=7 -> L=49, nW=64.
// Reference reassigns v = k. Outputs: score (2048*256*49) then attn
// (2048*8*49*49), fp32, concatenated in d_out.
//
// FINAL (= R13, the best harness-verified version; R14/R15 pipeline
// variants measured neutral-to-negative and were reverted).
//
// Session findings (counter-proven):
//  - Wall time tracks GLOBAL MEMORY INSTRUCTIONS through the per-CU TA
//    port (~0.7-0.9us per instr removed): loads 64->23 via global_load_lds
//    staging + K-read-once (-36us), stores 48->23 via LDS-routed
//    contiguous writeout (-17us). Below ~46 instr/wave the lever
//    saturates (R13 flat at ~22).
//  - Scratch spill is the #1 regression mode: launch_bounds-forced VGPR
//    caps or loop-carried state inflate FETCH/WRITE by 100s of MB
//    (tripwire: WRITE >> 256MB).
//  - Occupancy 23->52%, store patterns, prefetch consolidation, barrier
//    flavors, VALU cuts, I$ looping, 2-deep pipelines: all flat or
//    negative. Structure is distributed-latency-bound with all pipes
//    <40% busy at ~116us main-kernel time (pure-BW floor ~73us).
//
// Design: 4 waves, TWO bh per block.
//  stage:   raw K+Q to LDS via 7x global_load_lds dwordx4 per wave.
//  phase1:  S = Q^T K via mfma_f32_16x16x32_bf16 (RNE hi/lo bf16 split,
//           3 passes ~ fp32 accuracy), frags gathered from LDS raw.
//  epilogue: bf16 packed tables (frag-order, log2e-folded), no-max
//           softmax with native exp2 (|arg| bounded -> exact transform).
//  phase3:  score = K P^T from LDS-packed P hi/lo planes (XOR-swizzled);
//           K2 frags re-gathered from the same raw K (read once per bh).
//  writeout: attn as combined-pair float2 stream (LDS reconstruct
//           bf2f(hi)+bf2f(lo)); score staged f32 then float4 stream.
//  barriers: lgkm-only (no vmcnt drain) except the post-stage barrier.

#define LW 49
#define NH 8

typedef short s16x8 __attribute__((ext_vector_type(8)));
typedef float f32x4 __attribute__((ext_vector_type(4)));
typedef unsigned short u16x8 __attribute__((ext_vector_type(8)));

union Frag { s16x8 v; unsigned short u[8]; };

__device__ __forceinline__ unsigned short f2bf(float x) {
    return __builtin_bit_cast(unsigned short, __float2bfloat16(x));
}
__device__ __forceinline__ float bf2f(unsigned short h) {
    return __uint_as_float(((unsigned)h) << 16);
}
// hi = bf16(x); lo = bf16(x - hi). 3-pass MFMA (Ah*Bh + Al*Bh + Ah*Bl)
// gives ~fp32 accuracy.
__device__ __forceinline__ void split8(const float* xf, Frag& hi, Frag& lo) {
    #pragma unroll
    for (int j = 0; j < 8; j++) {
        const unsigned short hb = f2bf(xf[j]);
        hi.u[j] = hb;
        lo.u[j] = f2bf(xf[j] - bf2f(hb));
    }
}

// LDS-only barrier: does NOT drain vmcnt (global loads/stores keep flying).
__device__ __forceinline__ void lds_barrier() {
    asm volatile("s_waitcnt lgkmcnt(0)" ::: "memory");
    __builtin_amdgcn_s_barrier();
    asm volatile("" ::: "memory");
    __builtin_amdgcn_sched_barrier(0);
}
// Stage barrier: drains vmcnt too (global_load_lds lands via vmcnt).
// Placed BEFORE table loads are issued, so only staging is drained.
__device__ __forceinline__ void stage_barrier() {
    asm volatile("s_waitcnt vmcnt(0) lgkmcnt(0)" ::: "memory");
    __builtin_amdgcn_s_barrier();
    asm volatile("" ::: "memory");
    __builtin_amdgcn_sched_barrier(0);
}

__device__ __forceinline__ void load_lds16(const void* g, void* l) {
    __builtin_amdgcn_global_load_lds(
        (const __attribute__((address_space(1))) void*)g,
        (__attribute__((address_space(3))) void*)l, 16, 0, 0);
}

#define MFMA16(A, B, C) __builtin_amdgcn_mfma_f32_16x16x32_bf16((A), (B), (C), 0, 0, 0)

// ---------------- prep: bias & mask -> bf16, [x][mt][lane][nt*4+r] ----------
// Packed so one u16x8 (16B) load covers two nt-chunks. log2e-folded.
__global__ __launch_bounds__(256) void prep_frag_kernel(
    const float* __restrict__ mask, const float* __restrict__ table,
    const int* __restrict__ idx,
    unsigned short* __restrict__ biasB, unsigned short* __restrict__ maskB)
{
    const int i = blockIdx.x * 256 + threadIdx.x;
    const int NBF = 8 * 4096;        // 32768
    const int NMF = 64 * 4096;       // 262144
    const float L2E = 1.4426950408889634f;
    if (i < NBF) {
        const int h = i >> 12, rem = i & 4095;
        const int mt = rem >> 10, lane = (rem >> 4) & 63, e = rem & 15;
        const int nt = e >> 2, r = e & 3;
        const int t = mt * 16 + (lane >> 4) * 4 + r;
        const int s = nt * 16 + (lane & 15);
        const float v = (t < LW && s < LW)
                      ? table[idx[t * LW + s] * NH + h] * L2E : 0.f;
        biasB[i] = f2bf(v);
    } else if (i < NBF + NMF) {
        const int j = i - NBF;
        const int w2 = j >> 12, rem = j & 4095;
        const int mt = rem >> 10, lane = (rem >> 4) & 63, e = rem & 15;
        const int nt = e >> 2, r = e & 3;
        const int t = mt * 16 + (lane >> 4) * 4 + r;
        const int s = nt * 16 + (lane & 15);
        const float v = (t < LW && s < LW)
                      ? mask[w2 * (LW * LW) + t * LW + s] * L2E : 0.f;
        maskB[j] = f2bf(v);
    }
}

// ---------------- main: 4 waves, TWO bh per block ---------------------------
__global__ __launch_bounds__(256, 4) void wa_mfma_kernel(
    const float* __restrict__ q, const float* __restrict__ k,
    const unsigned short* __restrict__ biasB,
    const unsigned short* __restrict__ maskB,
    float* __restrict__ score_out, float* __restrict__ attn_out)
{
    // Per-bh 12800 B sub-buffer, three overlapping uses (barrier-protected):
    //  stage:    raw K fp32 [0,6400), raw Q fp32 [6400,12800)
    //  P planes: pHi u16 [0,6272)B, pLo u16 [6272,12544)B   (after phase 1)
    //  score:    f32 [0,6272)B                              (after phase 3)
    __shared__ __align__(16) char sRaw[2][12800];

    const int tid  = (int)threadIdx.x;    // 0..255
    const int wv   = __builtin_amdgcn_readfirstlane(tid >> 6);   // 0..3
    const int sub  = wv >> 1;             // which bh of the pair
    const int wvL  = wv & 1;              // role within the bh
    const int bh   = blockIdx.x * 2 + sub;
    const int h    = bh & 7;
    const int w    = (bh >> 3) & 63;
    const int lane = tid & 63;
    const int l15  = lane & 15;
    const int g4   = lane >> 4;

    const float* qp = q + (size_t)bh * (32 * LW);
    const float* kp = k + (size_t)bh * (32 * LW);

    char* ldsBase = &sRaw[sub][0];
    char* ldsK = ldsBase;
    char* ldsQ = ldsBase + 6400;

    // ==== stage raw K (wvL=0) / raw Q (wvL=1) via global_load_lds ====
    {
        const char* src = (wvL == 0) ? (const char*)kp : (const char*)qp;
        char*       dst = (wvL == 0) ? ldsK : ldsQ;
        #pragma unroll
        for (int i = 0; i < 6; i++)
            load_lds16(src + i * 1024 + lane * 16, dst + i * 1024);
        if (lane < 16) {
            // tail [6144,6400): lanes 8..15 write pad, gptr clamped in-bounds
            const int off = (lane < 8) ? lane * 16 : 112;
            load_lds16(src + 6144 + off, dst + 6144);
        }
    }

    stage_barrier();   // staging landed (all 4 waves); tables not yet issued

    // ==== bias/mask bf16 loads: u16x8 (16B), 8 instr/wave total ====
    u16x8 bq8[2][2], mq8[2][2];
    {
        const unsigned short* bF = biasB + (size_t)h * 4096;
        const unsigned short* mF = maskB + (size_t)w * 4096;
        #pragma unroll
        for (int mi = 0; mi < 2; mi++) {
            const int mt = wvL * 2 + mi;
            const u16x8* bp = (const u16x8*)(bF + mt * 1024 + lane * 16);
            const u16x8* mp = (const u16x8*)(mF + mt * 1024 + lane * 16);
            bq8[mi][0] = bp[0];
            bq8[mi][1] = bp[1];
            mq8[mi][0] = mp[0];
            mq8[mi][1] = mp[1];
        }
    }

    const float* sKf = (const float*)ldsK;
    const float* sQf = (const float*)ldsQ;

    // ==== Q frags from LDS raw ====
    Frag Qh[2], Ql[2];
    #pragma unroll
    for (int mi = 0; mi < 2; mi++) {
        const int t  = (wvL * 2 + mi) * 16 + l15;
        const int tc = t < LW ? t : (LW - 1);
        float xf[8];
        #pragma unroll
        for (int j = 0; j < 8; j++) xf[j] = sQf[(g4 * 8 + j) * LW + tc];
        split8(xf, Qh[mi], Ql[mi]);
    }

    // ==== phase 1: S rows of this wave (K frags gathered per nt) ====
    f32x4 acc[2][4];
    #pragma unroll
    for (int mi = 0; mi < 2; mi++)
        #pragma unroll
        for (int nt = 0; nt < 4; nt++)
            #pragma unroll
            for (int r = 0; r < 4; r++) acc[mi][nt][r] = 0.f;

    #pragma unroll
    for (int nt = 0; nt < 4; nt++) {
        const int s  = nt * 16 + l15;
        const int sc = s < LW ? s : (LW - 1);
        float xf[8];
        #pragma unroll
        for (int j = 0; j < 8; j++) xf[j] = sKf[(g4 * 8 + j) * LW + sc];
        Frag Kh, Kl;
        split8(xf, Kh, Kl);
        #pragma unroll
        for (int mi = 0; mi < 2; mi++) {
            acc[mi][nt] = MFMA16(Qh[mi].v, Kh.v, acc[mi][nt]);
            acc[mi][nt] = MFMA16(Ql[mi].v, Kh.v, acc[mi][nt]);
            acc[mi][nt] = MFMA16(Qh[mi].v, Kl.v, acc[mi][nt]);
        }
    }

    // ==== K2 frags from the SAME raw K (before P pack overwrites it) ====
    Frag K2h[2], K2l[2];
    {
        const int c = wvL * 16 + l15;                  // c < 32 always
        #pragma unroll
        for (int ks = 0; ks < 2; ks++) {
            float xf[8];
            #pragma unroll
            for (int j = 0; j < 8; j++) {
                const int s  = ks * 32 + g4 * 8 + j;
                const int sc = s < LW ? s : (LW - 1);  // P at pad s is 0
                xf[j] = sKf[c * LW + sc];
            }
            split8(xf, K2h[ks], K2l[ks]);
        }
    }

    // ==== scale2 + bias + mask (bf16 unpack); pad cols -> -1e30 ====
    const float scale2 = 0.17677669529663687f * 1.4426950408889634f;
    #pragma unroll
    for (int mi = 0; mi < 2; mi++) {
        #pragma unroll
        for (int nt = 0; nt < 4; nt++) {
            const bool pad = (nt * 16 + l15) >= LW;
            #pragma unroll
            for (int r = 0; r < 4; r++) {
                const float bm = bf2f(bq8[mi][nt >> 1][(nt & 1) * 4 + r])
                               + bf2f(mq8[mi][nt >> 1][(nt & 1) * 4 + r]);
                const float v2 = fmaf(acc[mi][nt][r], scale2, bm);
                acc[mi][nt][r] = pad ? -1e30f : v2;
            }
        }
    }

    // ==== softmax over s, no max-pass, native exp2 (exact transform) ====
    #pragma unroll
    for (int mi = 0; mi < 2; mi++) {
        #pragma unroll
        for (int r = 0; r < 4; r++) {
            float sm = 0.f;
            #pragma unroll
            for (int nt = 0; nt < 4; nt++) {
                const float p = __builtin_exp2f(acc[mi][nt][r]);
                acc[mi][nt][r] = p;
                sm += p;
            }
            sm += __shfl_xor(sm, 1);
            sm += __shfl_xor(sm, 2);
            sm += __shfl_xor(sm, 4);
            sm += __shfl_xor(sm, 8);
            const float inv = 1.0f / sm;
            #pragma unroll
            for (int nt = 0; nt < 4; nt++) acc[mi][nt][r] *= inv;
        }
    }

    lds_barrier();   // #2: all raw-LDS reads done; reuse sub-buffers for P

    // ==== pack this wave's P rows into hi/lo planes (swizzled); acc dies ====
    unsigned short* sB = (unsigned short*)ldsBase;
    #pragma unroll
    for (int mi = 0; mi < 2; mi++) {
        #pragma unroll
        for (int r = 0; r < 4; r++) {
            const int t = (wvL * 2 + mi) * 16 + g4 * 4 + r;
            if (t < LW) {
                #pragma unroll
                for (int nt = 0; nt < 4; nt++) {
                    const int s = nt * 16 + l15;
                    const float p = acc[mi][nt][r];
                    const unsigned short ph = f2bf(p);
                    const unsigned short pl = f2bf(p - bf2f(ph));
                    const unsigned idx = (unsigned)t * 64u
                        + ((((unsigned)s >> 3) ^ ((unsigned)t & 7u)) << 3)
                        + ((unsigned)s & 7u);
                    sB[idx]        = ph;
                    sB[3136 + idx] = pl;
                }
            }
        }
    }

    lds_barrier();   // #3: P staged for BOTH bh

    // ==== attn writeout: combined pair stream, float2 (8B-aligned) ====
    // value = bf2f(hi)+bf2f(lo) (validated reconstruct, err ~2^-17).
    // 2401 float2 slots over 256 threads = 10 instr/block (~5/bh).
    {
        float2* dst2 = (float2*)(attn_out + (size_t)(blockIdx.x * 2) * (LW * LW));
        #pragma unroll
        for (int it = 0; it < 10; it++) {
            const int j = it * 256 + tid;
            if (j < LW * LW) {                         // 2401 slots
                float v2[2];
                #pragma unroll
                for (int e = 0; e < 2; e++) {
                    const int g  = 2 * j + e;
                    const int sg = g >= LW * LW;       // which bh of pair
                    const int i2 = g - sg * (LW * LW);
                    const int t  = i2 / LW;            // magic-mul div
                    const int s  = i2 - t * LW;
                    const unsigned idx = (unsigned)t * 64u
                        + ((((unsigned)s >> 3) ^ ((unsigned)t & 7u)) << 3)
                        + ((unsigned)s & 7u);
                    const unsigned short* sBg = (const unsigned short*)&sRaw[sg][0];
                    v2[e] = bf2f(sBg[idx]) + bf2f(sBg[3136 + idx]);
                }
                dst2[j] = make_float2(v2[0], v2[1]);
            }
        }
    }

    // ==== phase 3: score(c,t) = sum_s K(c,s) P(t,s); A-frags via b128 ====
    // attn stores above overlap these MFMAs (lgkm barriers don't drain vm).
    f32x4 acc2[4];
    #pragma unroll
    for (int nt = 0; nt < 4; nt++)
        #pragma unroll
        for (int r = 0; r < 4; r++) acc2[nt][r] = 0.f;

    #pragma unroll
    for (int ntt = 0; ntt < 4; ntt++) {
        const int t  = ntt * 16 + l15;
        const int tr = t < LW ? t : (LW - 1);          // clamped dead cols
        #pragma unroll
        for (int ks = 0; ks < 2; ks++) {
            const unsigned base = (unsigned)tr * 64u
                + (((unsigned)(ks * 4 + g4) ^ ((unsigned)tr & 7u)) << 3);
            Frag Ph, Pl;
            Ph.v = *(const s16x8*)&sB[base];            // ds_read_b128
            Pl.v = *(const s16x8*)&sB[3136 + base];     // ds_read_b128
            acc2[ntt] = MFMA16(K2h[ks].v, Ph.v, acc2[ntt]);
            acc2[ntt] = MFMA16(K2l[ks].v, Ph.v, acc2[ntt]);
            acc2[ntt] = MFMA16(K2h[ks].v, Pl.v, acc2[ntt]);
        }
    }

    lds_barrier();   // #4: all P reads (attn writeout + phase 3) done

    // ==== stage score f32 into [0,6272) of own sub (pHi region, dead) ====
    float* scf = (float*)ldsBase;
    #pragma unroll
    for (int ntt = 0; ntt < 4; ntt++) {
        const int t = ntt * 16 + l15;
        if (t < LW) {
            #pragma unroll
            for (int r = 0; r < 4; r++) {
                const int c = wvL * 16 + g4 * 4 + r;
                scf[c * LW + t] = acc2[ntt][r];
            }
        }
    }

    lds_barrier();   // #5: score staged for BOTH bh

    // ==== score writeout: combined pair stream, float4 (16B-aligned) ====
    // 784 float4 slots over 256 threads = 4 instr/block (~2/bh).
    {
        float4* dst4 = (float4*)(score_out + (size_t)(blockIdx.x * 2) * (32 * LW));
        #pragma unroll
        for (int it = 0; it < 4; it++) {
            const int j = it * 256 + tid;
            if (j < 784) {                             // 2*6272B/16B
                const int sg = j >= 392;               // which bh of pair
                const float4* src4 = (const float4*)&sRaw[sg][0];
                dst4[j] = src4[j - sg * 392];
            }
        }
    }
}

// ---------------- fallback (ws too small): VALU kernel ----------------------
__global__ __launch_bounds__(256, 4) void wa_fallback_kernel(
    const float* __restrict__ q, const float* __restrict__ k,
    const float* __restrict__ mask0, const float* __restrict__ table,
    const int* __restrict__ idx,
    float* __restrict__ score_out, float* __restrict__ attn_out)
{
    __shared__ float sPf[LW * LW];
    const int lane = threadIdx.x & 63;
    const int wv   = __builtin_amdgcn_readfirstlane((int)(threadIdx.x >> 6));
    const int bh   = blockIdx.x * 4 + wv;
    const int h    = bh & 7;
    const int w    = (bh >> 3) & 63;
    const int t    = lane;
    const int tc   = (t < LW) ? t : (LW - 1);

    const float* qp = q + (size_t)bh * (32 * LW);
    const float* kp = k + (size_t)bh * (32 * LW);

    float qreg[32];
    #pragma unroll
    for (int c = 0; c < 32; c++) qreg[c] = qp[c * LW + tc];

    float S[LW];
    #pragma unroll
    for (int s = 0; s < LW; s++) S[s] = 0.f;
    #pragma unroll
    for (int c = 0; c < 32; c++) {
        #pragma unroll
        for (int s = 0; s < LW; s++)
            S[s] = fmaf(qreg[c], kp[c * LW + s], S[s]);
    }

    const float scale = 0.17677669529663687f;
    const float* mrow = mask0 + (size_t)w * (LW * LW) + tc * LW;
    const int*   irow = idx + tc * LW;
    #pragma unroll
    for (int s = 0; s < LW; s++) {
        const float bm = table[irow[s] * NH + h] + mrow[s];
        S[s] = fmaf(S[s], scale, bm);
    }

    float m = S[0];
    #pragma unroll
    for (int s = 1; s < LW; s++) m = fmaxf(m, S[s]);
    float sum = 0.f;
    #pragma unroll
    for (int s = 0; s < LW; s++) { S[s] = __expf(S[s] - m); sum += S[s]; }
    const float invs = 1.0f / sum;
    #pragma unroll
    for (int s = 0; s < LW; s++) S[s] *= invs;

    float* attn_base = attn_out + (size_t)bh * (LW * LW);
    for (int turn = 0; turn < 4; turn++) {
        __syncthreads();
        if (turn == wv) {
            if (t < LW) {
                #pragma unroll
                for (int s = 0; s < LW; s++) sPf[t * LW + s] = S[s];
            }
            #pragma unroll
            for (int it = 0; it < 38; it++) {
                const int i = it * 64 + lane;
                if (i < LW * LW) attn_base[i] = sPf[i];
            }
        }
    }

    float* sc = score_out + (size_t)bh * (32 * LW);
    #pragma unroll
    for (int c = 0; c < 32; c++) {
        float a = 0.f;
        #pragma unroll
        for (int s = 0; s < LW; s++) a = fmaf(S[s], kp[c * LW + s], a);
        if (t < LW) sc[c * LW + t] = a;
    }
}

extern "C" void kernel_launch(void* const* d_in, const int* in_sizes, int n_in,
                              void* d_out, int out_size, void* d_ws, size_t ws_size,
                              hipStream_t stream) {
    const float* q     = (const float*)d_in[0];
    const float* k     = (const float*)d_in[1];
    // d_in[2] = v, unused: reference reassigns v = k
    const float* mask  = (const float*)d_in[3];
    const float* table = (const float*)d_in[4];
    const int*   idx   = (const int*)d_in[5];

    float* score_out = (float*)d_out;
    float* attn_out  = score_out + (size_t)2048 * 256 * 49;

    const size_t NBF = (size_t)8 * 4096;     // 32768 bf16 elems
    const size_t NMF = (size_t)64 * 4096;    // 262144 bf16 elems

    if (ws_size >= (NBF + NMF) * sizeof(unsigned short)) {
        unsigned short* biasB = (unsigned short*)d_ws;
        unsigned short* maskB = biasB + NBF;
        const int tot = (int)(NBF + NMF);
        prep_frag_kernel<<<(tot + 255) / 256, 256, 0, stream>>>(
            mask, table, idx, biasB, maskB);
        wa_mfma_kernel<<<8192, 256, 0, stream>>>(
            q, k, biasB, maskB, score_out, attn_out);
    } else {
        wa_fallback_kernel<<<4096, 256, 0, stream>>>(
            q, k, mask, table, idx, score_out, attn_out);
    }
}